// Round 2
// baseline (1558.384 us; speedup 1.0000x reference)
//
#include <hip/hip_runtime.h>

#define NEG_SLOPE 0.2f

// ---------------- CSR construction ----------------

__global__ void k_init(float* deg, int* cnt, int* pos, int N){
  int i = blockIdx.x*blockDim.x + threadIdx.x;
  if (i < N){ deg[i] = 1.0f; cnt[i] = 0; pos[i] = 0; }
}

__global__ void k_edge_stats(const int* __restrict__ dst, const float* __restrict__ ew,
                             float* deg, int* cnt, int E){
  int e = blockIdx.x*blockDim.x + threadIdx.x;
  if (e < E){
    int d = dst[e];
    atomicAdd(&deg[d], ew[e]);
    atomicAdd(&cnt[d], 1);
  }
}

// single block of 1024; N <= 8192
__global__ void k_scan(const float* __restrict__ deg, const int* __restrict__ cnt,
                       float* dinv, float* loop_attr, int* row_ptr, int N){
  const int T = 1024, PER = 8;
  __shared__ int ssum[T];
  int tid = threadIdx.x;
  int base = tid*PER;
  int loc[PER]; int s = 0;
  #pragma unroll
  for (int u=0;u<PER;u++){
    int i = base+u;
    int c = (i<N)? cnt[i] : 0;
    loc[u] = s; s += c;
    if (i<N){
      float d = deg[i];
      dinv[i] = rsqrtf(d);
      loop_attr[i] = (d - 1.0f) / fmaxf((float)c, 1.0f);
    }
  }
  ssum[tid] = s; __syncthreads();
  for (int off=1; off<T; off<<=1){
    int t = (tid>=off)? ssum[tid-off] : 0;
    __syncthreads();
    ssum[tid] += t;
    __syncthreads();
  }
  int excl = ssum[tid] - s;
  #pragma unroll
  for (int u=0;u<PER;u++){ int i=base+u; if (i<N) row_ptr[i] = excl + loc[u]; }
  if (tid == T-1) row_ptr[N] = ssum[T-1];
}

__global__ void k_scatter(const int* __restrict__ dst, const int* __restrict__ row_ptr,
                          int* pos, int* edge_id, int E){
  int e = blockIdx.x*blockDim.x + threadIdx.x;
  if (e < E){
    int d = dst[e];
    int p = row_ptr[d] + atomicAdd(&pos[d], 1);
    edge_id[p] = e;
  }
}

// ---------------- generic fp32 GEMM:  C[M,N2] = A[M,K] * B[N2,K]^T ----------------
// 128x128 tile, 256 threads, 8x8 per thread, K staged in 32-chunks.
// As: [r][k] pad 36 (conflict-free b128 along k). Bs: transposed [k][j] pad 132.

template<int K>
__global__ __launch_bounds__(256)
void k_mm(const float* __restrict__ A, int lda, const float* __restrict__ B, int ldb,
          float* __restrict__ C, int M, int N2){
  __shared__ float As[128*36];
  __shared__ float Bs[32*132];
  int tid = threadIdx.x;
  int bi = blockIdx.y*128, bj = blockIdx.x*128;
  int tx = tid & 15, ty = tid >> 4;
  float acc[8][8] = {};

  for (int kh = 0; kh < K; kh += 32){
    for (int t = tid; t < 1024; t += 256){
      int r = t >> 3, k4 = (t & 7) << 2;
      int gr = bi + r;
      float4 v = (gr < M) ? *(const float4*)(A + (size_t)gr*lda + kh + k4)
                          : make_float4(0.f,0.f,0.f,0.f);
      *(float4*)(As + r*36 + k4) = v;
    }
    for (int t = tid; t < 1024; t += 256){
      int r = t >> 3, k4 = (t & 7) << 2;
      int gr = bj + r;
      float4 v = (gr < N2) ? *(const float4*)(B + (size_t)gr*ldb + kh + k4)
                           : make_float4(0.f,0.f,0.f,0.f);
      Bs[(k4+0)*132 + r] = v.x;
      Bs[(k4+1)*132 + r] = v.y;
      Bs[(k4+2)*132 + r] = v.z;
      Bs[(k4+3)*132 + r] = v.w;
    }
    __syncthreads();
    #pragma unroll
    for (int k = 0; k < 32; k += 4){
      float4 a4[8];
      #pragma unroll
      for (int u=0; u<4; u++){
        a4[u]   = *(const float4*)(As + (ty*4+u)*36 + k);
        a4[u+4] = *(const float4*)(As + (64+ty*4+u)*36 + k);
      }
      #pragma unroll
      for (int i=0; i<4; i++){
        float4 bl = *(const float4*)(Bs + (k+i)*132 + tx*4);
        float4 bh = *(const float4*)(Bs + (k+i)*132 + 64 + tx*4);
        #pragma unroll
        for (int u=0; u<8; u++){
          float av = (i==0)?a4[u].x : (i==1)?a4[u].y : (i==2)?a4[u].z : a4[u].w;
          acc[u][0] += av*bl.x; acc[u][1] += av*bl.y;
          acc[u][2] += av*bl.z; acc[u][3] += av*bl.w;
          acc[u][4] += av*bh.x; acc[u][5] += av*bh.y;
          acc[u][6] += av*bh.z; acc[u][7] += av*bh.w;
        }
      }
    }
    __syncthreads();
  }

  #pragma unroll
  for (int u=0; u<8; u++){
    int gi = bi + ((u<4) ? (ty*4+u) : (64+ty*4+(u-4)));
    if (gi >= M) continue;
    #pragma unroll
    for (int half=0; half<2; half++){
      int gj = bj + ((half==0) ? tx*4 : 64+tx*4);
      int v0 = half*4;
      if (gj + 4 <= N2){
        *(float4*)(C + (size_t)gi*N2 + gj) =
          make_float4(acc[u][v0],acc[u][v0+1],acc[u][v0+2],acc[u][v0+3]);
      } else {
        for (int v=0; v<4; v++) if (gj+v < N2) C[(size_t)gi*N2+gj+v] = acc[u][v0+v];
      }
    }
  }
}

// ---------------- GCN aggregation: wave per dst node, lane = feature ----------------

__global__ void k_gcn_agg(const float* __restrict__ h, const float* __restrict__ dinv,
                          const int* __restrict__ row_ptr, const int* __restrict__ edge_id,
                          const int* __restrict__ src, const float* __restrict__ ew,
                          const float* __restrict__ b, float* __restrict__ out,
                          int ostride, int ooff, int N){
  int wid = (blockIdx.x*blockDim.x + threadIdx.x) >> 6;
  int f = threadIdx.x & 63;
  if (wid >= N) return;
  float dn = dinv[wid];
  float acc = dn*dn*h[(size_t)wid*64 + f];
  int p0 = row_ptr[wid], p1 = row_ptr[wid+1];
  for (int p=p0; p<p1; p++){
    int e = edge_id[p];
    int s = src[e];
    float nrm = dinv[s]*ew[e]*dn;
    acc += nrm * h[(size_t)s*64 + f];
  }
  out[(size_t)wid*ostride + ooff + f] = fmaxf(acc + b[f], 0.f);
}

// ---------------- GAT attention logits per node ----------------

__global__ void k_al(const float* __restrict__ hg, const float* __restrict__ gas,
                     const float* __restrict__ gad, float* al_s, float* al_d, int N){
  int wid = (blockIdx.x*blockDim.x + threadIdx.x) >> 6;
  int f = threadIdx.x & 63;
  if (wid >= N) return;
  #pragma unroll
  for (int hh=0; hh<4; hh++){
    float v = hg[(size_t)wid*256 + hh*64 + f];
    float ps = v * gas[hh*64+f];
    float pd = v * gad[hh*64+f];
    #pragma unroll
    for (int off=32; off>0; off>>=1){ ps += __shfl_down(ps,off); pd += __shfl_down(pd,off); }
    if (f==0){ al_s[wid*4+hh] = ps; al_d[wid*4+hh] = pd; }
  }
}

// ce[h] = sum_f We[h*64+f] * a_edge[h,f]   (single wave)
__global__ void k_ce(const float* __restrict__ gaeW, const float* __restrict__ gae, float* ce){
  int f = threadIdx.x;
  #pragma unroll
  for (int hh=0; hh<4; hh++){
    float v = gaeW[hh*64+f] * gae[hh*64+f];
    #pragma unroll
    for (int off=32; off>0; off>>=1) v += __shfl_down(v,off);
    if (f==0) ce[hh] = v;
  }
}

// ---------------- GAT aggregation with online softmax ----------------

__global__ void k_gat_agg(const float* __restrict__ hg, const float* __restrict__ al_s,
                          const float* __restrict__ al_d, const float* __restrict__ loop_attr,
                          const float* __restrict__ ce, const int* __restrict__ row_ptr,
                          const int* __restrict__ edge_id, const int* __restrict__ src,
                          const float* __restrict__ ew, const float* __restrict__ b,
                          float* __restrict__ out, int N){
  int wid = (blockIdx.x*blockDim.x + threadIdx.x) >> 6;
  int f = threadIdx.x & 63;
  if (wid >= N) return;
  float4 cv = *(const float4*)ce;
  float c[4] = {cv.x, cv.y, cv.z, cv.w};
  float4 adv = *(const float4*)(al_d + (size_t)wid*4);
  float ad[4] = {adv.x, adv.y, adv.z, adv.w};
  float4 asv = *(const float4*)(al_s + (size_t)wid*4);
  float as_[4] = {asv.x, asv.y, asv.z, asv.w};
  float la = loop_attr[wid];

  float m[4], l[4], acc[4];
  const float* hn = hg + (size_t)wid*256;
  #pragma unroll
  for (int hh=0; hh<4; hh++){
    float a = as_[hh] + ad[hh] + la*c[hh];
    a = (a >= 0.f) ? a : NEG_SLOPE*a;
    m[hh] = a; l[hh] = 1.f;
    acc[hh] = hn[hh*64 + f];
  }
  int p0 = row_ptr[wid], p1 = row_ptr[wid+1];
  for (int p=p0; p<p1; p++){
    int e = edge_id[p];
    int s = src[e];
    float w = ew[e];
    const float* hs = hg + (size_t)s*256;
    float4 asf = *(const float4*)(al_s + (size_t)s*4);
    float av[4] = {asf.x, asf.y, asf.z, asf.w};
    #pragma unroll
    for (int hh=0; hh<4; hh++){
      float a = av[hh] + ad[hh] + w*c[hh];
      a = (a >= 0.f) ? a : NEG_SLOPE*a;
      float mn = fmaxf(m[hh], a);
      float sc = __expf(m[hh] - mn);
      float fc = __expf(a - mn);
      acc[hh] = acc[hh]*sc + hs[hh*64+f]*fc;
      l[hh] = l[hh]*sc + fc;
      m[hh] = mn;
    }
  }
  float o = 0.25f*(acc[0]/l[0] + acc[1]/l[1] + acc[2]/l[2] + acc[3]/l[3]);
  out[(size_t)wid*64 + f] = fmaxf(o + b[f], 0.f);
}

// ---------------- bias add ----------------

__global__ void k_bias(float* fea, const float* __restrict__ b, int total){
  int i = blockIdx.x*blockDim.x + threadIdx.x;
  if (i < total) fea[i] += b[i & 63];
}

// ---------------- launcher ----------------

extern "C" void kernel_launch(void* const* d_in, const int* in_sizes, int n_in,
                              void* d_out, int out_size, void* d_ws, size_t ws_size,
                              hipStream_t stream){
  const float* x_cir  = (const float*)d_in[0];
  const float* x_drug = (const float*)d_in[1];
  const float* x_dis  = (const float*)d_in[2];
  const int*   cir_edges  = (const int*)d_in[3];
  const float* cir_ew     = (const float*)d_in[4];
  const int*   drug_edges = (const int*)d_in[5];
  const float* drug_ew    = (const float*)d_in[6];
  const int*   dis_edges  = (const int*)d_in[7];
  const float* dis_ew     = (const float*)d_in[8];
  const float* gcn_cir1_W = (const float*)d_in[9];
  const float* gcn_cir1_b = (const float*)d_in[10];
  const float* gcn_cir2_W = (const float*)d_in[11];
  const float* gcn_cir2_b = (const float*)d_in[12];
  const float* gcn_dis1_W = (const float*)d_in[13];
  const float* gcn_dis1_b = (const float*)d_in[14];
  const float* gcn_dis2_W = (const float*)d_in[15];
  const float* gcn_dis2_b = (const float*)d_in[16];
  const float* gat_cir_W    = (const float*)d_in[17];
  const float* gat_cir_asrc = (const float*)d_in[18];
  const float* gat_cir_adst = (const float*)d_in[19];
  const float* gat_cir_eW   = (const float*)d_in[20];
  const float* gat_cir_aedge= (const float*)d_in[21];
  const float* gat_cir_b    = (const float*)d_in[22];
  const float* gat_dis_W    = (const float*)d_in[23];
  const float* gat_dis_asrc = (const float*)d_in[24];
  const float* gat_dis_adst = (const float*)d_in[25];
  const float* gat_dis_eW   = (const float*)d_in[26];
  const float* gat_dis_aedge= (const float*)d_in[27];
  const float* gat_dis_b    = (const float*)d_in[28];
  const float* cnn_cir_W = (const float*)d_in[29];
  const float* cnn_cir_b = (const float*)d_in[30];
  const float* cnn_dis_W = (const float*)d_in[31];
  const float* cnn_dis_b = (const float*)d_in[32];
  float* out = (float*)d_out;

  const int Nc=8000, Nd=6000, Ns=6000, Ec=256000, Ed=192000, Es=192000;

  char* wp = (char*)d_ws;
  auto alloc = [&](size_t bytes)->void*{
    void* p = wp; wp += (bytes + 255) & ~(size_t)255; return p;
  };
  float* deg  = (float*)alloc(8000*4);
  float* dinv = (float*)alloc(8000*4);
  float* lat  = (float*)alloc(8000*4);
  int*   cnt  = (int*)alloc(8000*4);
  int*   pos  = (int*)alloc(8000*4);
  int*   rowp = (int*)alloc(8001*4);
  int*   eid  = (int*)alloc(256000*4);
  float* ce_c = (float*)alloc(64);
  float* ce_d = (float*)alloc(64);
  float* als  = (float*)alloc(8000*4*4);
  float* ald  = (float*)alloc(8000*4*4);
  float* hbuf = (float*)alloc((size_t)8000*256*4);   // h1 / hg / h2
  float* f12  = (float*)alloc((size_t)8000*128*4);   // [f1 | f2] per node
  float* att  = (float*)alloc((size_t)8000*64*4);

  // fea written directly into d_out tail
  float* fea_c = out + 132000000ULL;
  float* fea_d = out + 132512000ULL;
  float* fea_s = out + 132896000ULL;

  k_ce<<<1,64,0,stream>>>(gat_cir_eW, gat_cir_aedge, ce_c);
  k_ce<<<1,64,0,stream>>>(gat_dis_eW, gat_dis_aedge, ce_d);

  struct BR {
    const float* x; const int* edges; const float* ew; int N, E;
    const float* g1W; const float* g1b; const float* g2W; const float* g2b;
    const float* gaW; const float* gas; const float* gad; const float* gab;
    const float* ce; const float* cW; const float* cb; float* fea;
  };
  BR brs[3] = {
    { x_cir,  cir_edges,  cir_ew,  Nc, Ec, gcn_cir1_W, gcn_cir1_b, gcn_cir2_W, gcn_cir2_b,
      gat_cir_W, gat_cir_asrc, gat_cir_adst, gat_cir_b, ce_c, cnn_cir_W, cnn_cir_b, fea_c },
    { x_drug, drug_edges, drug_ew, Nd, Ed, gcn_dis1_W, gcn_dis1_b, gcn_dis2_W, gcn_dis2_b,
      gat_dis_W, gat_dis_asrc, gat_dis_adst, gat_dis_b, ce_d, cnn_dis_W, cnn_dis_b, fea_d },
    { x_dis,  dis_edges,  dis_ew,  Ns, Es, gcn_dis1_W, gcn_dis1_b, gcn_dis2_W, gcn_dis2_b,
      gat_dis_W, gat_dis_asrc, gat_dis_adst, gat_dis_b, ce_d, cnn_dis_W, cnn_dis_b, fea_s },
  };

  for (int b=0; b<3; b++){
    const BR& B = brs[b];
    const int* srcp = B.edges;
    const int* dstp = B.edges + B.E;
    int nb  = (B.N + 255)/256;
    int eb  = (B.E + 255)/256;
    int wb  = (B.N*64 + 255)/256;   // wave-per-node kernels
    int mb  = (B.N + 127)/128;      // GEMM row tiles

    k_init<<<nb,256,0,stream>>>(deg, cnt, pos, B.N);
    k_edge_stats<<<eb,256,0,stream>>>(dstp, B.ew, deg, cnt, B.E);
    k_scan<<<1,1024,0,stream>>>(deg, cnt, dinv, lat, rowp, B.N);
    k_scatter<<<eb,256,0,stream>>>(dstp, rowp, pos, eid, B.E);

    // GCN1: h1 = x @ g1W^T   -> aggregate -> f1 (into f12[:, 0:64])
    k_mm<64><<<dim3(1,mb),256,0,stream>>>(B.x, 64, B.g1W, 64, hbuf, B.N, 64);
    k_gcn_agg<<<wb,256,0,stream>>>(hbuf, dinv, rowp, eid, srcp, B.ew, B.g1b,
                                   f12, 128, 0, B.N);
    // GAT: hg = f1 @ gaW^T  (f1 read from f12 with lda=128)
    k_mm<64><<<dim3(2,mb),256,0,stream>>>(f12, 128, B.gaW, 64, hbuf, B.N, 256);
    k_al<<<wb,256,0,stream>>>(hbuf, B.gas, B.gad, als, ald, B.N);
    k_gat_agg<<<wb,256,0,stream>>>(hbuf, als, ald, lat, B.ce, rowp, eid, srcp,
                                   B.ew, B.gab, att, B.N);
    // GCN2: h2 = att @ g2W^T -> aggregate -> f2 (into f12[:, 64:128])
    k_mm<64><<<dim3(1,mb),256,0,stream>>>(att, 64, B.g2W, 64, hbuf, B.N, 64);
    k_gcn_agg<<<wb,256,0,stream>>>(hbuf, dinv, rowp, eid, srcp, B.ew, B.g2b,
                                   f12, 128, 64, B.N);
    // readout: fea = [f1|f2] @ cnnW^T  (bias added by k_bias below)
    k_mm<128><<<dim3(1,mb),256,0,stream>>>(f12, 128, B.cW, 128, B.fea, B.N, 64);
  }

  // add readout biases
  k_bias<<<(Nc*64+255)/256,256,0,stream>>>(fea_c, cnn_cir_b, Nc*64);
  k_bias<<<(Nd*64+255)/256,256,0,stream>>>(fea_d, cnn_dis_b, Nd*64);
  k_bias<<<(Ns*64+255)/256,256,0,stream>>>(fea_s, cnn_dis_b, Ns*64);

  // final score matrices
  k_mm<64><<<dim3((6000+127)/128,(8000+127)/128),256,0,stream>>>(fea_c, 64, fea_s, 64, out,                8000, 6000);
  k_mm<64><<<dim3((6000+127)/128,(8000+127)/128),256,0,stream>>>(fea_c, 64, fea_d, 64, out + 48000000ULL,  8000, 6000);
  k_mm<64><<<dim3((6000+127)/128,(6000+127)/128),256,0,stream>>>(fea_d, 64, fea_s, 64, out + 96000000ULL,  6000, 6000);
}